// Round 10
// baseline (5747.715 us; speedup 1.0000x reference)
//
#include <hip/hip_runtime.h>
#include <math.h>

#define HDIM  1024
#define VDIM  50257
#define NBLK  256
#define NTHR  1024
#define NWAVE 16
#define LROWS 128

typedef unsigned int uint;

// ---------------- ws layout ----------------
#define WS_GATES   0         // 2*4096 f32 (double-buffered gates)
#define WS_PSOFT   32768     // 256 f32
#define WS_PARGV   33792     // 256 f32
#define WS_PARGI   34816     // 256 i32
#define WS_PSUM    35840     // 256 f32
#define WS_ARRE    36864     // encoder arrive: 256*128B
#define WS_DONE_E  69632     // encoder done: 32*128B
#define WS_ARRD    73728     // decoder arrive: 256*128B
#define WS_DONE_D  106496    // decoder done: 32*128B (+payload)
#define WS_HC      110592    // h(4KB) + c(4KB) encoder->decoder handoff
#define WS_ZOFF    32768
#define WS_ZLEN    77824     // zero 32768..110592 each launch
#define WS_W8      131072    // fp8 e4m3 W_out
#define W8_BYTES   ((size_t)VDIM * HDIM)

#if __has_builtin(__builtin_amdgcn_cvt_pk_f32_fp8) && __has_builtin(__builtin_amdgcn_cvt_pk_fp8_f32)
#define FP8_HW 1
#else
#define FP8_HW 0
#endif

__device__ __forceinline__ float dot4(float4 a, float4 b) {
  return a.x * b.x + a.y * b.y + a.z * b.z + a.w * b.w;
}

#if !FP8_HW
__device__ __forceinline__ float fp8d(uint b) {
  uint em = b & 0x7fu;
  float m;
  if (em >= 8u) m = __uint_as_float(((((em >> 3) + 120u) << 23) | ((em & 7u) << 20)));
  else          m = (float)em * 0.001953125f;
  return (b & 0x80u) ? -m : m;
}
__device__ __forceinline__ uint fp8e(float x) {
  uint s = (__float_as_uint(x) >> 24) & 0x80u;
  float ax = fabsf(x);
  uint r;
  if (ax < 0.015625f) {
    r = (uint)rintf(ax * 512.f);
  } else {
    uint b = __float_as_uint(ax);
    b += 0x7ffffu + ((b >> 20) & 1u);
    int  e8 = (int)(b >> 23) - 127 + 7;
    uint m8 = (b >> 20) & 7u;
    if (e8 >= 16 || (e8 == 15 && m8 == 7u)) { e8 = 15; m8 = 6u; }
    r = ((uint)e8 << 3) | m8;
  }
  return r | s;
}
#endif

__device__ __forceinline__ float dot16_fp8(uint4 u, float4 h0, float4 h1,
                                           float4 h2, float4 h3) {
#if FP8_HW
  float s = 0.f;
  { auto a = __builtin_amdgcn_cvt_pk_f32_fp8((int)u.x, false);
    auto b = __builtin_amdgcn_cvt_pk_f32_fp8((int)u.x, true);
    s += a[0] * h0.x + a[1] * h0.y + b[0] * h0.z + b[1] * h0.w; }
  { auto a = __builtin_amdgcn_cvt_pk_f32_fp8((int)u.y, false);
    auto b = __builtin_amdgcn_cvt_pk_f32_fp8((int)u.y, true);
    s += a[0] * h1.x + a[1] * h1.y + b[0] * h1.z + b[1] * h1.w; }
  { auto a = __builtin_amdgcn_cvt_pk_f32_fp8((int)u.z, false);
    auto b = __builtin_amdgcn_cvt_pk_f32_fp8((int)u.z, true);
    s += a[0] * h2.x + a[1] * h2.y + b[0] * h2.z + b[1] * h2.w; }
  { auto a = __builtin_amdgcn_cvt_pk_f32_fp8((int)u.w, false);
    auto b = __builtin_amdgcn_cvt_pk_f32_fp8((int)u.w, true);
    s += a[0] * h3.x + a[1] * h3.y + b[0] * h3.z + b[1] * h3.w; }
  return s;
#else
  float s = 0.f;
  s += fp8d(u.x & 255u) * h0.x + fp8d((u.x >> 8) & 255u) * h0.y +
       fp8d((u.x >> 16) & 255u) * h0.z + fp8d(u.x >> 24) * h0.w;
  s += fp8d(u.y & 255u) * h1.x + fp8d((u.y >> 8) & 255u) * h1.y +
       fp8d((u.y >> 16) & 255u) * h1.z + fp8d(u.y >> 24) * h1.w;
  s += fp8d(u.z & 255u) * h2.x + fp8d((u.z >> 8) & 255u) * h2.y +
       fp8d((u.z >> 16) & 255u) * h2.z + fp8d(u.z >> 24) * h2.w;
  s += fp8d(u.w & 255u) * h3.x + fp8d((u.w >> 8) & 255u) * h3.y +
       fp8d((u.w >> 16) & 255u) * h3.z + fp8d(u.w >> 24) * h3.w;
  return s;
#endif
}

__device__ __forceinline__ float wred64(float v) {
  v += __shfl_xor(v, 32); v += __shfl_xor(v, 16); v += __shfl_xor(v, 8);
  v += __shfl_xor(v, 4);  v += __shfl_xor(v, 2);  v += __shfl_xor(v, 1);
  return v;
}

__device__ __forceinline__ void wmax64(float& v, int& i) {
#pragma unroll
  for (int off = 32; off > 0; off >>= 1) {
    float v2 = __shfl_xor(v, off);
    int   i2 = __shfl_xor(i, off);
    if (v2 > v || (v2 == v && i2 < i)) { v = v2; i = i2; }
  }
}

__device__ __forceinline__ float wvmax64(float v) {
#pragma unroll
  for (int off = 32; off > 0; off >>= 1) v = fmaxf(v, __shfl_xor(v, off));
  return v;
}

// ---- RELAXED agent-scope accessors (sc1, IC-coherent, no buffer_inv/wbl2) ----
__device__ __forceinline__ uint ald(const uint* p) {
  return __hip_atomic_load(p, __ATOMIC_RELAXED, __HIP_MEMORY_SCOPE_AGENT);
}
__device__ __forceinline__ void ast(uint* p, uint v) {
  __hip_atomic_store(p, v, __ATOMIC_RELAXED, __HIP_MEMORY_SCOPE_AGENT);
}
__device__ __forceinline__ float aldf(const float* p) {
  return __hip_atomic_load(p, __ATOMIC_RELAXED, __HIP_MEMORY_SCOPE_AGENT);
}
__device__ __forceinline__ void astf(float* p, float v) {
  __hip_atomic_store(p, v, __ATOMIC_RELAXED, __HIP_MEMORY_SCOPE_AGENT);
}
__device__ __forceinline__ int aldi(const int* p) {
  return __hip_atomic_load(p, __ATOMIC_RELAXED, __HIP_MEMORY_SCOPE_AGENT);
}
__device__ __forceinline__ void asti(int* p, int v) {
  __hip_atomic_store(p, v, __ATOMIC_RELAXED, __HIP_MEMORY_SCOPE_AGENT);
}
__device__ __forceinline__ void fence_vm() {
  asm volatile("s_waitcnt vmcnt(0)" ::: "memory");
}

// Fence-free grid barrier (proven R5/R6).
__device__ __forceinline__ void gbar(uint* arrive, uint* done, uint r) {
  __syncthreads();
  if (blockIdx.x == 0) {
    const int tid = threadIdx.x;
    if (tid >= 1 && tid < NBLK) {
      const uint* slot = arrive + tid * 32;
      while (ald(slot) < r) __builtin_amdgcn_s_sleep(1);
    }
    __syncthreads();
    if (tid < 32) ast(done + tid * 32, r);
  } else {
    if (threadIdx.x == 0) {
      fence_vm();
      ast(arrive + blockIdx.x * 32, r);
      const uint* dl = done + (blockIdx.x >> 3) * 32;
      while (ald(dl) < r) __builtin_amdgcn_s_sleep(1);
    }
    __syncthreads();
  }
}

// fp32 -> fp8 e4m3 (RNE) converter
__global__ void conv8_kernel(const float* __restrict__ W,
                             uint4* __restrict__ o, int n16) {
  int i = blockIdx.x * blockDim.x + threadIdx.x;
  int stride = gridDim.x * blockDim.x;
  const float4* W4 = (const float4*)W;
  for (; i < n16; i += stride) {
    float4 f0 = W4[4 * i], f1 = W4[4 * i + 1], f2 = W4[4 * i + 2], f3 = W4[4 * i + 3];
    uint4 u;
#if FP8_HW
    int p;
    p = __builtin_amdgcn_cvt_pk_fp8_f32(f0.x, f0.y, 0, false);
    p = __builtin_amdgcn_cvt_pk_fp8_f32(f0.z, f0.w, p, true);  u.x = (uint)p;
    p = __builtin_amdgcn_cvt_pk_fp8_f32(f1.x, f1.y, 0, false);
    p = __builtin_amdgcn_cvt_pk_fp8_f32(f1.z, f1.w, p, true);  u.y = (uint)p;
    p = __builtin_amdgcn_cvt_pk_fp8_f32(f2.x, f2.y, 0, false);
    p = __builtin_amdgcn_cvt_pk_fp8_f32(f2.z, f2.w, p, true);  u.z = (uint)p;
    p = __builtin_amdgcn_cvt_pk_fp8_f32(f3.x, f3.y, 0, false);
    p = __builtin_amdgcn_cvt_pk_fp8_f32(f3.z, f3.w, p, true);  u.w = (uint)p;
#else
    u.x = fp8e(f0.x) | (fp8e(f0.y) << 8) | (fp8e(f0.z) << 16) | (fp8e(f0.w) << 24);
    u.y = fp8e(f1.x) | (fp8e(f1.y) << 8) | (fp8e(f1.z) << 16) | (fp8e(f1.w) << 24);
    u.z = fp8e(f2.x) | (fp8e(f2.y) << 8) | (fp8e(f2.z) << 16) | (fp8e(f2.w) << 24);
    u.w = fp8e(f3.x) | (fp8e(f3.y) << 8) | (fp8e(f3.z) << 16) | (fp8e(f3.w) << 24);
#endif
    o[i] = u;
  }
}

// ======================= encoder kernel =======================
__attribute__((amdgpu_waves_per_eu(4, 4)))
__global__ void __launch_bounds__(NTHR)
enc_kernel(const int* __restrict__ source, int S,
           const float* __restrict__ Wemb_enc,
           const float* __restrict__ W_ih_e, const float* __restrict__ W_hh_e,
           const float* __restrict__ b_ih_e, const float* __restrict__ b_hh_e,
           float* gates, uint* arrive, uint* done, float* hc)
{
  const int tid  = threadIdx.x;
  const int blk  = blockIdx.x;
  const int wave = tid >> 6;
  const int lane = tid & 63;

  __shared__ float4 x4[2][HDIM / 4];
  __shared__ float4 h4[HDIM / 4];
  __shared__ float  c_lds[HDIM];

  float* h_s = (float*)h4;
  h_s[tid] = 0.f;
  c_lds[tid] = 0.f;

  const int r_e = blk * NWAVE + wave;
  float4 wie[4], whe[4];
  {
    const float4* pie = (const float4*)(W_ih_e + (size_t)r_e * HDIM);
    const float4* phe = (const float4*)(W_hh_e + (size_t)r_e * HDIM);
#pragma unroll
    for (int c = 0; c < 4; ++c) {
      wie[c] = pie[lane + 64 * c];
      whe[c] = phe[lane + 64 * c];
    }
  }
  const float bse = b_ih_e[r_e] + b_hh_e[r_e];

  if (tid < 256)
    x4[0][tid] = ((const float4*)(Wemb_enc + (size_t)source[0] * HDIM))[tid];
  __syncthreads();

  uint rnd = 0;
  int gstep = 0, xb = 0;

  for (int t = 0; t < S; ++t) {
    float4 pf;
    const bool havepf = (t + 1 < S) && (tid < 256);
    if (havepf)
      pf = ((const float4*)(Wemb_enc + (size_t)source[t + 1] * HDIM))[tid];

    float g = bse;
    const float4* xf = (const float4*)&x4[xb][0];
#pragma unroll
    for (int c = 0; c < 4; ++c) {
      g += dot4(wie[c], xf[lane + 64 * c]);
      g += dot4(whe[c], h4[lane + 64 * c]);
    }
    g = wred64(g);
    float* gcur = gates + (gstep & 1) * 4096;
    if (lane == 0) astf(&gcur[r_e], g);

    gbar(arrive, done, ++rnd);

    {
      float ig = aldf(&gcur[tid]),        fg = aldf(&gcur[tid + 1024]);
      float gv = aldf(&gcur[tid + 2048]), og = aldf(&gcur[tid + 3072]);
      float ii = 1.f / (1.f + expf(-ig));
      float ff = 1.f / (1.f + expf(-fg));
      float gt = tanhf(gv);
      float oo = 1.f / (1.f + expf(-og));
      float cc = ff * c_lds[tid] + ii * gt;
      c_lds[tid] = cc;
      h_s[tid]   = oo * tanhf(cc);
    }
    if (havepf) x4[xb ^ 1][tid] = pf;
    __syncthreads();
    xb ^= 1;
    ++gstep;
  }

  if (blk == 0 && tid < 256) {
    ((float4*)hc)[tid]       = ((float4*)h_s)[tid];
    ((float4*)hc)[256 + tid] = ((float4*)c_lds)[tid];
  }
}

// ======================= decoder kernel =======================
// Designed to FIT IN 64 VGPRs (R7-R9 lesson: the allocator refuses >64 at
// 1024 threads; pinned LSTM weights spilled to scratch -> 227MB/launch of
// scratch traffic). LSTM weights are now STREAMED (L2-resident 128KB/block);
// only the step-invariant W8 rows 128..191 stay VGPR-pinned (16 regs).
// MODE 2: fp8, 128 rows in LDS + 64 rows in VGPRs + 4-5 rows streamed.
// MODE 1: fp8 global-stream fallback. MODE 0: fp32 fallback.
template <int MODE>
__attribute__((amdgpu_waves_per_eu(4, 4)))
__global__ void __launch_bounds__(NTHR)
dec_kernel(const int* __restrict__ n_steps_p, const int* __restrict__ start_tok_p,
           const float* __restrict__ Wemb_dec,
           const float* __restrict__ W_ih_d, const float* __restrict__ W_hh_d,
           const float* __restrict__ b_ih_d, const float* __restrict__ b_hh_d,
           const float* __restrict__ W_out, const float* __restrict__ b_out,
           const uint4* __restrict__ W8,
           float* __restrict__ out,
           float* gates, float* psoft, float* pargv, int* pargi, float* psum,
           uint* arrive, uint* done, const float* __restrict__ hc)
{
  const int tid  = threadIdx.x;
  const int blk  = blockIdx.x;
  const int wave = tid >> 6;
  const int lane = tid & 63;

  __shared__ float4 x4[HDIM / 4];
  __shared__ float4 h4[HDIM / 4];
  __shared__ float  hscan[HDIM];
  __shared__ float  c_l[HDIM];
  __shared__ float  e_l[200];
  __shared__ float  bo_l[200];
  __shared__ float  red_v[NWAVE];
  __shared__ int    red_i[NWAVE];
  __shared__ float  red_s[NWAVE];
  __shared__ float  red_n[NWAVE];
  __shared__ float  red_v2[NWAVE];
  __shared__ int    red_i2[NWAVE];
  __shared__ int    sh_tok;
  __shared__ float  sh_lmax;
  __shared__ float  sh_S;
  extern __shared__ uint4 w8l[];   // MODE 2: LROWS*64 uint4 (128 KB)

  float* h_s = (float*)h4;

  const int nsteps = n_steps_p[0];
  const int r_d = blk * NWAVE + wave;
  const float bsd = b_ih_d[r_d] + b_hh_d[r_d];

  // streamed LSTM weight row pointers (L2-resident; NOT pinned -> no spill)
  const float4* pid = (const float4*)(W_ih_d + (size_t)r_d * HDIM);
  const float4* phd = (const float4*)(W_hh_d + (size_t)r_d * HDIM);

  const int start = blk * 196 + (blk < 81 ? blk : 81);
  const int count = 196 + (blk < 81 ? 1 : 0);

  if (tid < 256) {
    h4[tid]             = ((const float4*)hc)[tid];
    ((float4*)c_l)[tid] = ((const float4*)hc)[256 + tid];
  }
  for (int j = tid; j < count; j += NTHR) bo_l[j] = b_out[start + j];

  // MODE 2: one-time LDS fill + pinned batch (rows 128+4w..131+4w, 16 VGPR)
  uint4 g0, g1, g2, g3;
  bool haveq = false;
  const uint4* qp = nullptr;
  if (MODE == 2) {
    const uint4* src = W8 + ((size_t)start << 6);
    for (int idx = tid; idx < LROWS * 64; idx += NTHR) w8l[idx] = src[idx];
    const uint4* gp = W8 + (((size_t)(start + 128 + 4 * wave)) << 6) + lane;
    g0 = gp[0]; g1 = gp[64]; g2 = gp[128]; g3 = gp[192];
    haveq = wave < (count - 192);           // 4 or 5 leftover rows
    qp = W8 + (((size_t)(start + 192 + wave)) << 6) + lane;
  }

  float4 pfx;
  if (tid < 256)
    pfx = ((const float4*)(Wemb_dec + (size_t)start_tok_p[0] * HDIM))[tid];
  __syncthreads();

  uint rnd = 0;
  int gstep = 0;

  for (int t = 0; t < nsteps; ++t) {
    if (tid < 256) x4[tid] = pfx;
    __syncthreads();

    // ---- LSTM gates (weights streamed; 8 f4 loads in flight) ----
    {
      float g = bsd;
#pragma unroll
      for (int c = 0; c < 4; ++c) {
        g += dot4(pid[lane + 64 * c], x4[lane + 64 * c]);
        g += dot4(phd[lane + 64 * c], h4[lane + 64 * c]);
      }
      g = wred64(g);
      float* gcur = gates + (gstep & 1) * 4096;
      if (lane == 0) astf(&gcur[r_d], g);
    }
    gbar(arrive, done, ++rnd);  // (A)

    // issue leftover-row load EARLY: hides under gates read + activations
    uint4 qv;
    if (MODE == 2 && haveq) qv = qp[0];

    {
      const float* gcur = gates + (gstep & 1) * 4096;
      float ig = aldf(&gcur[tid]),        fg = aldf(&gcur[tid + 1024]);
      float gv = aldf(&gcur[tid + 2048]), og = aldf(&gcur[tid + 3072]);
      float ii = 1.f / (1.f + expf(-ig));
      float ff = 1.f / (1.f + expf(-fg));
      float gt = tanhf(gv);
      float oo = 1.f / (1.f + expf(-og));
      float cc = ff * c_l[tid] + ii * gt;
      c_l[tid] = cc;
      float hv = oo * tanhf(cc);
      h_s[tid] = hv;
      hscan[((((tid >> 2) ^ ((tid >> 5) & 7)) << 2) | (tid & 3))] = hv;
      float h2 = wred64(hv * hv);
      if (lane == 0) red_n[wave] = h2;
    }
    ++gstep;
    __syncthreads();

    // ---- logit scan ----
    if (MODE >= 1) {
      const float4* hs4 = (const float4*)hscan;
      const int c0 = 4 * lane;
      float4 h0 = hs4[(c0 + 0) ^ (((c0 + 0) >> 3) & 7)];
      float4 h1 = hs4[(c0 + 1) ^ (((c0 + 1) >> 3) & 7)];
      float4 h2 = hs4[(c0 + 2) ^ (((c0 + 2) >> 3) & 7)];
      float4 h3 = hs4[(c0 + 3) ^ (((c0 + 3) >> 3) & 7)];
      if (MODE == 2) {
        // pinned batch first (rows 128+4w..131+4w, register-resident)
        {
          int jb = 4 * wave + 128;
          float a0 = dot16_fp8(g0, h0, h1, h2, h3);
          float a1 = dot16_fp8(g1, h0, h1, h2, h3);
          float a2 = dot16_fp8(g2, h0, h1, h2, h3);
          float a3 = dot16_fp8(g3, h0, h1, h2, h3);
          a0 = wred64(a0); a1 = wred64(a1); a2 = wred64(a2); a3 = wred64(a3);
          if (lane == 0) {
            e_l[jb]     = a0 + bo_l[jb];
            e_l[jb + 1] = a1 + bo_l[jb + 1];
            e_l[jb + 2] = a2 + bo_l[jb + 2];
            e_l[jb + 3] = a3 + bo_l[jb + 3];
          }
        }
        // 2 LDS batches (rows 0..127)
#pragma unroll
        for (int k = 0; k < 2; ++k) {
          int jb = 4 * wave + 64 * k;
          const uint4* b0 = w8l + (jb << 6) + lane;
          uint4 u0 = b0[0], u1 = b0[64], u2 = b0[128], u3 = b0[192];
          float a0 = dot16_fp8(u0, h0, h1, h2, h3);
          float a1 = dot16_fp8(u1, h0, h1, h2, h3);
          float a2 = dot16_fp8(u2, h0, h1, h2, h3);
          float a3 = dot16_fp8(u3, h0, h1, h2, h3);
          a0 = wred64(a0); a1 = wred64(a1); a2 = wred64(a2); a3 = wred64(a3);
          if (lane == 0) {
            e_l[jb]     = a0 + bo_l[jb];
            e_l[jb + 1] = a1 + bo_l[jb + 1];
            e_l[jb + 2] = a2 + bo_l[jb + 2];
            e_l[jb + 3] = a3 + bo_l[jb + 3];
          }
        }
        // leftover rows 192..count-1, one row per wave
        if (haveq) {
          float a = dot16_fp8(qv, h0, h1, h2, h3);
          a = wred64(a);
          if (lane == 0) e_l[192 + wave] = a + bo_l[192 + wave];
        }
      } else {  // MODE 1: fp8 global stream
        for (int jb = wave * 4; jb < count; jb += 64) {
          int n_ = count - jb;
          const uint4* b0 = W8 + (((size_t)(start + jb)) << 6) + lane;
          uint4 u0 = b0[0];
          uint4 u1 = b0[n_ > 1 ? 64 : 0];
          uint4 u2 = b0[n_ > 2 ? 128 : 0];
          uint4 u3 = b0[n_ > 3 ? 192 : 0];
          float a0 = dot16_fp8(u0, h0, h1, h2, h3);
          float a1 = dot16_fp8(u1, h0, h1, h2, h3);
          float a2 = dot16_fp8(u2, h0, h1, h2, h3);
          float a3 = dot16_fp8(u3, h0, h1, h2, h3);
          a0 = wred64(a0); a1 = wred64(a1); a2 = wred64(a2); a3 = wred64(a3);
          if (lane == 0) {
            e_l[jb] = a0 + bo_l[jb];
            if (n_ > 1) e_l[jb + 1] = a1 + bo_l[jb + 1];
            if (n_ > 2) e_l[jb + 2] = a2 + bo_l[jb + 2];
            if (n_ > 3) e_l[jb + 3] = a3 + bo_l[jb + 3];
          }
        }
      }
    } else {  // MODE 0: fp32 global
      for (int jb = wave * 4; jb < count; jb += 64) {
        int n_ = count - jb;
        const float4* r0 = (const float4*)(W_out + (size_t)(start + jb) * HDIM);
        const float4* r1 = (const float4*)(W_out + (size_t)(start + jb + (n_ > 1 ? 1 : 0)) * HDIM);
        const float4* r2 = (const float4*)(W_out + (size_t)(start + jb + (n_ > 2 ? 2 : 0)) * HDIM);
        const float4* r3 = (const float4*)(W_out + (size_t)(start + jb + (n_ > 3 ? 3 : 0)) * HDIM);
        float a0 = 0.f, a1 = 0.f, a2 = 0.f, a3 = 0.f;
#pragma unroll
        for (int c = 0; c < 4; ++c) {
          float4 hh = h4[lane + 64 * c];
          a0 += dot4(r0[lane + 64 * c], hh);
          a1 += dot4(r1[lane + 64 * c], hh);
          a2 += dot4(r2[lane + 64 * c], hh);
          a3 += dot4(r3[lane + 64 * c], hh);
        }
        a0 = wred64(a0); a1 = wred64(a1); a2 = wred64(a2); a3 = wred64(a3);
        if (lane == 0) {
          e_l[jb] = a0 + bo_l[jb];
          if (n_ > 1) e_l[jb + 1] = a1 + bo_l[jb + 1];
          if (n_ > 2) e_l[jb + 2] = a2 + bo_l[jb + 2];
          if (n_ > 3) e_l[jb + 3] = a3 + bo_l[jb + 3];
        }
      }
    }
    __syncthreads();

    // ---- block-local max/argmax (np.argmax tie-break: lowest index) ----
    float m_soft; int i_soft;
    {
      float v = -INFINITY; int idx = 0x7fffffff;
      if (tid < count) { v = e_l[tid]; idx = start + tid; }
      wmax64(v, idx);
      if (lane == 0) { red_v[wave] = v; red_i[wave] = idx; }
    }
    __syncthreads();
    {
      float v = red_v[0]; int idx = red_i[0];
#pragma unroll
      for (int w = 1; w < NWAVE; ++w) {
        float v2 = red_v[w]; int i2 = red_i[w];
        if (v2 > v || (v2 == v && i2 < idx)) { v = v2; idx = i2; }
      }
      m_soft = v; i_soft = idx;
    }

    // ---- exp partial ----
    float pe = (tid < count) ? expf(e_l[tid] - m_soft) : 0.f;
    {
      float ls = wred64(pe);
      if (lane == 0) red_s[wave] = ls;
    }

    // ---- fp32 rescore of near-max candidates (argmax-exact) ----
    float m_arg = m_soft; int i_arg = i_soft;
    if (MODE >= 1) {
      float nrm2 = 0.f;
#pragma unroll
      for (int w = 0; w < NWAVE; ++w) nrm2 += red_n[w];
      float delta = 0.005f * sqrtf(nrm2) + 1e-6f;   // ~10 sigma of fp8 error
      float bv = -INFINITY; int bi = 0x7fffffff;
      for (int j = wave; j < count; j += NWAVE) {
        if (e_l[j] >= m_soft - delta) {
          const float4* w = (const float4*)(W_out + (size_t)(start + j) * HDIM);
          float a = 0.f;
#pragma unroll
          for (int c = 0; c < 4; ++c) a += dot4(w[lane + 64 * c], h4[lane + 64 * c]);
          a = wred64(a) + bo_l[j];
          if (a > bv) { bv = a; bi = start + j; }
        }
      }
      if (lane == 0) { red_v2[wave] = bv; red_i2[wave] = bi; }
    }
    __syncthreads();
    float lsum = 0.f;
#pragma unroll
    for (int w = 0; w < NWAVE; ++w) lsum += red_s[w];
    if (MODE >= 1) {
      float v = red_v2[0]; int idx = red_i2[0];
#pragma unroll
      for (int w = 1; w < NWAVE; ++w) {
        float v2 = red_v2[w]; int i2 = red_i2[w];
        if (v2 > v || (v2 == v && i2 < idx)) { v = v2; idx = i2; }
      }
      m_arg = v; i_arg = idx;
    }

    if (tid == 0) {
      astf(&psoft[blk], m_soft); astf(&pargv[blk], m_arg);
      asti(&pargi[blk], i_arg);  astf(&psum[blk], lsum);
    }

    // ---- barrier B with payload ----
    ++rnd;
    __syncthreads();
    int tokn; float lmax, Ssum;
    if (blk == 0) {
      if (tid >= 1 && tid < NBLK) {
        const uint* slot = arrive + tid * 32;
        while (ald(slot) < rnd) __builtin_amdgcn_s_sleep(1);
      }
      __syncthreads();
      float v = -INFINITY, m = -INFINITY, mysum = 0.f, myms = 0.f;
      int idx = 0x7fffffff;
      if (tid < NBLK) {
        v     = aldf(&pargv[tid]);
        idx   = aldi(&pargi[tid]);
        m     = aldf(&psoft[tid]);
        mysum = aldf(&psum[tid]);
        myms  = m;
      }
      wmax64(v, idx);
      float mm = wvmax64(m);
      if (lane == 0 && wave < 4) { red_v[wave] = v; red_i[wave] = idx; red_n[wave] = mm; }
      __syncthreads();
      {
        float vv = red_v[0]; int ii2 = red_i[0]; float mmax = red_n[0];
#pragma unroll
        for (int w = 1; w < 4; ++w) {
          float v2 = red_v[w]; int i2 = red_i[w];
          if (v2 > vv || (v2 == vv && i2 < ii2)) { vv = v2; ii2 = i2; }
          mmax = fmaxf(mmax, red_n[w]);
        }
        tokn = ii2; lmax = mmax;
      }
      {
        float s = (tid < NBLK) ? mysum * expf(myms - lmax) : 0.f;
        s = wred64(s);
        if (lane == 0 && wave < 4) red_s[wave] = s;
      }
      __syncthreads();
      Ssum = red_s[0] + red_s[1] + red_s[2] + red_s[3];
      if (tid < 32) {
        uint* dl = done + tid * 32;
        ast(dl + 1, (uint)tokn);
        ast(dl + 2, __float_as_uint(lmax));
        ast(dl + 3, __float_as_uint(Ssum));
        fence_vm();
        ast(dl, rnd);
      }
    } else {
      if (tid == 0) {
        fence_vm();
        ast(arrive + blk * 32, rnd);
        const uint* dl = done + (blk >> 3) * 32;
        while (ald(dl) < rnd) __builtin_amdgcn_s_sleep(1);
        sh_tok  = (int)ald(dl + 1);
        sh_lmax = __uint_as_float(ald(dl + 2));
        sh_S    = __uint_as_float(ald(dl + 3));
      }
      __syncthreads();
      tokn = sh_tok; lmax = sh_lmax; Ssum = sh_S;
    }

    if (tid < 256)
      pfx = ((const float4*)(Wemb_dec + (size_t)tokn * HDIM))[tid];

    float scale = expf(m_soft - lmax) / Ssum;
    if (tid < count)
      out[(size_t)nsteps + (size_t)t * VDIM + start + tid] = pe * scale;
    if (blk == 0 && tid == 0) out[t] = (float)tokn;
  }
}

extern "C" void kernel_launch(void* const* d_in, const int* in_sizes, int n_in,
                              void* d_out, int out_size, void* d_ws, size_t ws_size,
                              hipStream_t stream) {
  const int*   source      = (const int*)d_in[0];
  const int*   n_steps_p   = (const int*)d_in[1];
  const int*   start_tok_p = (const int*)d_in[2];
  const float* Wemb_enc    = (const float*)d_in[3];
  const float* W_ih_e      = (const float*)d_in[4];
  const float* W_hh_e      = (const float*)d_in[5];
  const float* b_ih_e      = (const float*)d_in[6];
  const float* b_hh_e      = (const float*)d_in[7];
  const float* Wemb_dec    = (const float*)d_in[8];
  const float* W_ih_d      = (const float*)d_in[9];
  const float* W_hh_d      = (const float*)d_in[10];
  const float* b_ih_d      = (const float*)d_in[11];
  const float* b_hh_d      = (const float*)d_in[12];
  const float* W_out       = (const float*)d_in[13];
  const float* b_out       = (const float*)d_in[14];
  float*       out         = (float*)d_out;
  int          S           = in_sizes[0];

  char* ws = (char*)d_ws;
  float* gates  = (float*)(ws + WS_GATES);
  float* psoft  = (float*)(ws + WS_PSOFT);
  float* pargv  = (float*)(ws + WS_PARGV);
  int*   pargi  = (int*)  (ws + WS_PARGI);
  float* psum   = (float*)(ws + WS_PSUM);
  uint*  arrE   = (uint*) (ws + WS_ARRE);
  uint*  donE   = (uint*) (ws + WS_DONE_E);
  uint*  arrD   = (uint*) (ws + WS_ARRD);
  uint*  donD   = (uint*) (ws + WS_DONE_D);
  float* hc     = (float*)(ws + WS_HC);
  uint4* W8     = (uint4*)(ws + WS_W8);

  bool use_q8 = ws_size >= (size_t)WS_W8 + W8_BYTES;

  hipMemsetAsync(ws + WS_ZOFF, 0, WS_ZLEN, stream);

  if (use_q8)
    conv8_kernel<<<2048, 256, 0, stream>>>(W_out, W8, VDIM * HDIM / 16);

  void* eargs[] = { &source, &S, &Wemb_enc, &W_ih_e, &W_hh_e, &b_ih_e, &b_hh_e,
                    &gates, &arrE, &donE, &hc };
  hipLaunchCooperativeKernel((void*)enc_kernel, dim3(NBLK), dim3(NTHR),
                             eargs, 0, stream);

  void* dargs[] = { &n_steps_p, &start_tok_p, &Wemb_dec, &W_ih_d, &W_hh_d,
                    &b_ih_d, &b_hh_d, &W_out, &b_out, &W8, &out, &gates,
                    &psoft, &pargv, &pargi, &psum, &arrD, &donD, &hc };

  bool launched = false;
  if (use_q8) {
    int dyn = LROWS * 1024;   // 131072 B dynamic
    // attempt to raise the dynamic-LDS cap; IGNORE the return code (it can
    // report failure on ROCm while the launch itself succeeds) and instead
    // check the launch result directly.
    (void)hipFuncSetAttribute((const void*)dec_kernel<2>,
                              hipFuncAttributeMaxDynamicSharedMemorySize, dyn);
    hipError_t err = hipLaunchCooperativeKernel((void*)dec_kernel<2>,
                                                dim3(NBLK), dim3(NTHR),
                                                dargs, dyn, stream);
    if (err == hipSuccess) launched = true;
    else (void)hipGetLastError();   // clear error state
    if (!launched) {
      err = hipLaunchCooperativeKernel((void*)dec_kernel<1>, dim3(NBLK),
                                       dim3(NTHR), dargs, 0, stream);
      if (err == hipSuccess) launched = true;
    }
  }
  if (!launched) {
    hipLaunchCooperativeKernel((void*)dec_kernel<0>, dim3(NBLK), dim3(NTHR),
                               dargs, 0, stream);
  }
}

// Round 11
// 4393.127 us; speedup vs baseline: 1.3083x; 1.3083x over previous
//
#include <hip/hip_runtime.h>
#include <math.h>

#define HDIM  1024
#define VDIM  50257
#define NBLK  256
#define NTHR  1024      // encoder block size (unchanged, barrier-floor bound)
#define NTHR_D 512      // decoder block size: 512thr => 128-VGPR regime (R2/R4/R5)
#define NWAVE  16
#define NWAVE_D 8
#define LROWS  128

typedef unsigned int uint;

// ---------------- ws layout ----------------
#define WS_GATES   0         // 2*4096 f32 (double-buffered gates)
#define WS_PSOFT   32768     // 256 f32
#define WS_PARGV   33792     // 256 f32
#define WS_PARGI   34816     // 256 i32
#define WS_PSUM    35840     // 256 f32
#define WS_ARRE    36864     // encoder arrive: 256*128B
#define WS_DONE_E  69632     // encoder done: 32*128B
#define WS_ARRD    73728     // decoder arrive: 256*128B
#define WS_DONE_D  106496    // decoder done: 32*128B (+payload)
#define WS_HC      110592    // h(4KB) + c(4KB) encoder->decoder handoff
#define WS_ZOFF    32768
#define WS_ZLEN    77824     // zero 32768..110592 each launch
#define WS_W8      131072    // fp8 e4m3 W_out
#define W8_BYTES   ((size_t)VDIM * HDIM)

#if __has_builtin(__builtin_amdgcn_cvt_pk_f32_fp8) && __has_builtin(__builtin_amdgcn_cvt_pk_fp8_f32)
#define FP8_HW 1
#else
#define FP8_HW 0
#endif

__device__ __forceinline__ float dot4(float4 a, float4 b) {
  return a.x * b.x + a.y * b.y + a.z * b.z + a.w * b.w;
}

#if !FP8_HW
__device__ __forceinline__ float fp8d(uint b) {
  uint em = b & 0x7fu;
  float m;
  if (em >= 8u) m = __uint_as_float(((((em >> 3) + 120u) << 23) | ((em & 7u) << 20)));
  else          m = (float)em * 0.001953125f;
  return (b & 0x80u) ? -m : m;
}
__device__ __forceinline__ uint fp8e(float x) {
  uint s = (__float_as_uint(x) >> 24) & 0x80u;
  float ax = fabsf(x);
  uint r;
  if (ax < 0.015625f) {
    r = (uint)rintf(ax * 512.f);
  } else {
    uint b = __float_as_uint(ax);
    b += 0x7ffffu + ((b >> 20) & 1u);
    int  e8 = (int)(b >> 23) - 127 + 7;
    uint m8 = (b >> 20) & 7u;
    if (e8 >= 16 || (e8 == 15 && m8 == 7u)) { e8 = 15; m8 = 6u; }
    r = ((uint)e8 << 3) | m8;
  }
  return r | s;
}
#endif

__device__ __forceinline__ float dot16_fp8(uint4 u, float4 h0, float4 h1,
                                           float4 h2, float4 h3) {
#if FP8_HW
  float s = 0.f;
  { auto a = __builtin_amdgcn_cvt_pk_f32_fp8((int)u.x, false);
    auto b = __builtin_amdgcn_cvt_pk_f32_fp8((int)u.x, true);
    s += a[0] * h0.x + a[1] * h0.y + b[0] * h0.z + b[1] * h0.w; }
  { auto a = __builtin_amdgcn_cvt_pk_f32_fp8((int)u.y, false);
    auto b = __builtin_amdgcn_cvt_pk_f32_fp8((int)u.y, true);
    s += a[0] * h1.x + a[1] * h1.y + b[0] * h1.z + b[1] * h1.w; }
  { auto a = __builtin_amdgcn_cvt_pk_f32_fp8((int)u.z, false);
    auto b = __builtin_amdgcn_cvt_pk_f32_fp8((int)u.z, true);
    s += a[0] * h2.x + a[1] * h2.y + b[0] * h2.z + b[1] * h2.w; }
  { auto a = __builtin_amdgcn_cvt_pk_f32_fp8((int)u.w, false);
    auto b = __builtin_amdgcn_cvt_pk_f32_fp8((int)u.w, true);
    s += a[0] * h3.x + a[1] * h3.y + b[0] * h3.z + b[1] * h3.w; }
  return s;
#else
  float s = 0.f;
  s += fp8d(u.x & 255u) * h0.x + fp8d((u.x >> 8) & 255u) * h0.y +
       fp8d((u.x >> 16) & 255u) * h0.z + fp8d(u.x >> 24) * h0.w;
  s += fp8d(u.y & 255u) * h1.x + fp8d((u.y >> 8) & 255u) * h1.y +
       fp8d((u.y >> 16) & 255u) * h1.z + fp8d(u.y >> 24) * h1.w;
  s += fp8d(u.z & 255u) * h2.x + fp8d((u.z >> 8) & 255u) * h2.y +
       fp8d((u.z >> 16) & 255u) * h2.z + fp8d(u.z >> 24) * h2.w;
  s += fp8d(u.w & 255u) * h3.x + fp8d((u.w >> 8) & 255u) * h3.y +
       fp8d((u.w >> 16) & 255u) * h3.z + fp8d(u.w >> 24) * h3.w;
  return s;
#endif
}

__device__ __forceinline__ float wred32(float v) {
  v += __shfl_xor(v, 16); v += __shfl_xor(v, 8); v += __shfl_xor(v, 4);
  v += __shfl_xor(v, 2);  v += __shfl_xor(v, 1);
  return v;
}

__device__ __forceinline__ float wred64(float v) {
  v += __shfl_xor(v, 32); v += __shfl_xor(v, 16); v += __shfl_xor(v, 8);
  v += __shfl_xor(v, 4);  v += __shfl_xor(v, 2);  v += __shfl_xor(v, 1);
  return v;
}

__device__ __forceinline__ void wmax64(float& v, int& i) {
#pragma unroll
  for (int off = 32; off > 0; off >>= 1) {
    float v2 = __shfl_xor(v, off);
    int   i2 = __shfl_xor(i, off);
    if (v2 > v || (v2 == v && i2 < i)) { v = v2; i = i2; }
  }
}

__device__ __forceinline__ float wvmax64(float v) {
#pragma unroll
  for (int off = 32; off > 0; off >>= 1) v = fmaxf(v, __shfl_xor(v, off));
  return v;
}

// ---- RELAXED agent-scope accessors (sc1, IC-coherent, no buffer_inv/wbl2) ----
__device__ __forceinline__ uint ald(const uint* p) {
  return __hip_atomic_load(p, __ATOMIC_RELAXED, __HIP_MEMORY_SCOPE_AGENT);
}
__device__ __forceinline__ void ast(uint* p, uint v) {
  __hip_atomic_store(p, v, __ATOMIC_RELAXED, __HIP_MEMORY_SCOPE_AGENT);
}
__device__ __forceinline__ float aldf(const float* p) {
  return __hip_atomic_load(p, __ATOMIC_RELAXED, __HIP_MEMORY_SCOPE_AGENT);
}
__device__ __forceinline__ void astf(float* p, float v) {
  __hip_atomic_store(p, v, __ATOMIC_RELAXED, __HIP_MEMORY_SCOPE_AGENT);
}
__device__ __forceinline__ int aldi(const int* p) {
  return __hip_atomic_load(p, __ATOMIC_RELAXED, __HIP_MEMORY_SCOPE_AGENT);
}
__device__ __forceinline__ void asti(int* p, int v) {
  __hip_atomic_store(p, v, __ATOMIC_RELAXED, __HIP_MEMORY_SCOPE_AGENT);
}
__device__ __forceinline__ void fence_vm() {
  asm volatile("s_waitcnt vmcnt(0)" ::: "memory");
}

// Fence-free grid barrier (proven R5/R6).
__device__ __forceinline__ void gbar(uint* arrive, uint* done, uint r) {
  __syncthreads();
  if (blockIdx.x == 0) {
    const int tid = threadIdx.x;
    if (tid >= 1 && tid < NBLK) {
      const uint* slot = arrive + tid * 32;
      while (ald(slot) < r) __builtin_amdgcn_s_sleep(1);
    }
    __syncthreads();
    if (tid < 32) ast(done + tid * 32, r);
  } else {
    if (threadIdx.x == 0) {
      fence_vm();
      ast(arrive + blockIdx.x * 32, r);
      const uint* dl = done + (blockIdx.x >> 3) * 32;
      while (ald(dl) < r) __builtin_amdgcn_s_sleep(1);
    }
    __syncthreads();
  }
}

// fp32 -> fp8 e4m3 (RNE) converter
__global__ void conv8_kernel(const float* __restrict__ W,
                             uint4* __restrict__ o, int n16) {
  int i = blockIdx.x * blockDim.x + threadIdx.x;
  int stride = gridDim.x * blockDim.x;
  const float4* W4 = (const float4*)W;
  for (; i < n16; i += stride) {
    float4 f0 = W4[4 * i], f1 = W4[4 * i + 1], f2 = W4[4 * i + 2], f3 = W4[4 * i + 3];
    uint4 u;
#if FP8_HW
    int p;
    p = __builtin_amdgcn_cvt_pk_fp8_f32(f0.x, f0.y, 0, false);
    p = __builtin_amdgcn_cvt_pk_fp8_f32(f0.z, f0.w, p, true);  u.x = (uint)p;
    p = __builtin_amdgcn_cvt_pk_fp8_f32(f1.x, f1.y, 0, false);
    p = __builtin_amdgcn_cvt_pk_fp8_f32(f1.z, f1.w, p, true);  u.y = (uint)p;
    p = __builtin_amdgcn_cvt_pk_fp8_f32(f2.x, f2.y, 0, false);
    p = __builtin_amdgcn_cvt_pk_fp8_f32(f2.z, f2.w, p, true);  u.z = (uint)p;
    p = __builtin_amdgcn_cvt_pk_fp8_f32(f3.x, f3.y, 0, false);
    p = __builtin_amdgcn_cvt_pk_fp8_f32(f3.z, f3.w, p, true);  u.w = (uint)p;
#else
    u.x = fp8e(f0.x) | (fp8e(f0.y) << 8) | (fp8e(f0.z) << 16) | (fp8e(f0.w) << 24);
    u.y = fp8e(f1.x) | (fp8e(f1.y) << 8) | (fp8e(f1.z) << 16) | (fp8e(f1.w) << 24);
    u.z = fp8e(f2.x) | (fp8e(f2.y) << 8) | (fp8e(f2.z) << 16) | (fp8e(f2.w) << 24);
    u.w = fp8e(f3.x) | (fp8e(f3.y) << 8) | (fp8e(f3.z) << 16) | (fp8e(f3.w) << 24);
#endif
    o[i] = u;
  }
}

// ======================= encoder kernel (unchanged, 1024 thr) =======================
__global__ void __launch_bounds__(NTHR)
enc_kernel(const int* __restrict__ source, int S,
           const float* __restrict__ Wemb_enc,
           const float* __restrict__ W_ih_e, const float* __restrict__ W_hh_e,
           const float* __restrict__ b_ih_e, const float* __restrict__ b_hh_e,
           float* gates, uint* arrive, uint* done, float* hc)
{
  const int tid  = threadIdx.x;
  const int blk  = blockIdx.x;
  const int wave = tid >> 6;
  const int lane = tid & 63;

  __shared__ float4 x4[2][HDIM / 4];
  __shared__ float4 h4[HDIM / 4];
  __shared__ float  c_lds[HDIM];

  float* h_s = (float*)h4;
  h_s[tid] = 0.f;
  c_lds[tid] = 0.f;

  const int r_e = blk * NWAVE + wave;
  float4 wie[4], whe[4];
  {
    const float4* pie = (const float4*)(W_ih_e + (size_t)r_e * HDIM);
    const float4* phe = (const float4*)(W_hh_e + (size_t)r_e * HDIM);
#pragma unroll
    for (int c = 0; c < 4; ++c) {
      wie[c] = pie[lane + 64 * c];
      whe[c] = phe[lane + 64 * c];
    }
  }
  const float bse = b_ih_e[r_e] + b_hh_e[r_e];

  if (tid < 256)
    x4[0][tid] = ((const float4*)(Wemb_enc + (size_t)source[0] * HDIM))[tid];
  __syncthreads();

  uint rnd = 0;
  int gstep = 0, xb = 0;

  for (int t = 0; t < S; ++t) {
    float4 pf;
    const bool havepf = (t + 1 < S) && (tid < 256);
    if (havepf)
      pf = ((const float4*)(Wemb_enc + (size_t)source[t + 1] * HDIM))[tid];

    float g = bse;
    const float4* xf = (const float4*)&x4[xb][0];
#pragma unroll
    for (int c = 0; c < 4; ++c) {
      g += dot4(wie[c], xf[lane + 64 * c]);
      g += dot4(whe[c], h4[lane + 64 * c]);
    }
    g = wred64(g);
    float* gcur = gates + (gstep & 1) * 4096;
    if (lane == 0) astf(&gcur[r_e], g);

    gbar(arrive, done, ++rnd);

    {
      float ig = aldf(&gcur[tid]),        fg = aldf(&gcur[tid + 1024]);
      float gv = aldf(&gcur[tid + 2048]), og = aldf(&gcur[tid + 3072]);
      float ii = 1.f / (1.f + expf(-ig));
      float ff = 1.f / (1.f + expf(-fg));
      float gt = tanhf(gv);
      float oo = 1.f / (1.f + expf(-og));
      float cc = ff * c_lds[tid] + ii * gt;
      c_lds[tid] = cc;
      h_s[tid]   = oo * tanhf(cc);
    }
    if (havepf) x4[xb ^ 1][tid] = pf;
    __syncthreads();
    xb ^= 1;
    ++gstep;
  }

  if (blk == 0 && tid < 256) {
    ((float4*)hc)[tid]       = ((float4*)h_s)[tid];
    ((float4*)hc)[256 + tid] = ((float4*)c_lds)[tid];
  }
}

// ======================= decoder kernel (512 thr) =======================
// 512 threads => the allocator's 128-VGPR regime (proven R2/R4/R5; 1024-thr
// blocks are hard-capped at 64 VGPR on this toolchain and spill).
// LSTM weights VGPR-pinned (2 rows/wave half-wave layout, 64 VGPR, R2 pattern)
// -> zero per-step weight traffic -> L2 freed for the W8 leftover rows.
// MODE 2: rows 0..127 in LDS, rows 128..191 global (L2-resident 2.2MB/XCD),
//         rows 192+ one per wave, early-issued.
// MODE 1: fp8 global-stream fallback. MODE 0: fp32 fallback.
template <int MODE>
__global__ void __launch_bounds__(NTHR_D)
dec_kernel(const int* __restrict__ n_steps_p, const int* __restrict__ start_tok_p,
           const float* __restrict__ Wemb_dec,
           const float* __restrict__ W_ih_d, const float* __restrict__ W_hh_d,
           const float* __restrict__ b_ih_d, const float* __restrict__ b_hh_d,
           const float* __restrict__ W_out, const float* __restrict__ b_out,
           const uint4* __restrict__ W8,
           float* __restrict__ out,
           float* gates, float* psoft, float* pargv, int* pargi, float* psum,
           uint* arrive, uint* done, const float* __restrict__ hc)
{
  const int tid  = threadIdx.x;
  const int blk  = blockIdx.x;
  const int wave = tid >> 6;
  const int lane = tid & 63;
  const int l32  = lane & 31;
  const int rh   = lane >> 5;   // which of the wave's 2 LSTM rows

  __shared__ float4 x4[HDIM / 4];
  __shared__ float4 h4[HDIM / 4];
  __shared__ float  hscan[HDIM];
  __shared__ float  c_l[HDIM];
  __shared__ float  e_l[200];
  __shared__ float  bo_l[200];
  __shared__ float  red_v[NWAVE_D];
  __shared__ int    red_i[NWAVE_D];
  __shared__ float  red_s[NWAVE_D];
  __shared__ float  red_n[NWAVE_D];
  __shared__ float  red_v2[NWAVE_D];
  __shared__ int    red_i2[NWAVE_D];
  __shared__ int    sh_tok;
  __shared__ float  sh_lmax;
  __shared__ float  sh_S;
  extern __shared__ uint4 w8l[];   // MODE 2: LROWS*64 uint4 (128 KB)

  float* h_s = (float*)h4;

  const int nsteps = n_steps_p[0];
  const int r_d = blk * 16 + wave * 2 + rh;
  const float bsd = b_ih_d[r_d] + b_hh_d[r_d];

  // ---- pin decoder LSTM weight slice in VGPRs (R2 half-wave pattern, 64 VGPR) ----
  float4 wid[8], whd[8];
  {
    const float4* pid = (const float4*)(W_ih_d + (size_t)r_d * HDIM);
    const float4* phd = (const float4*)(W_hh_d + (size_t)r_d * HDIM);
#pragma unroll
    for (int c = 0; c < 8; ++c) {
      wid[c] = pid[l32 + 32 * c];
      whd[c] = phd[l32 + 32 * c];
    }
  }

  const int start = blk * 196 + (blk < 81 ? blk : 81);
  const int count = 196 + (blk < 81 ? 1 : 0);

  if (tid < 256) {
    h4[tid]             = ((const float4*)hc)[tid];
    ((float4*)c_l)[tid] = ((const float4*)hc)[256 + tid];
  }
  for (int j = tid; j < count; j += NTHR_D) bo_l[j] = b_out[start + j];

  // MODE 2: one-time LDS fill (rows 0..127)
  bool haveq = false;
  const uint4* qp = nullptr;
  if (MODE == 2) {
    const uint4* src = W8 + ((size_t)start << 6);
    for (int idx = tid; idx < LROWS * 64; idx += NTHR_D) w8l[idx] = src[idx];
    haveq = wave < (count - 192);           // 4 or 5 leftover rows
    qp = W8 + (((size_t)(start + 192 + wave)) << 6) + lane;
  }

  float4 pfx;
  if (tid < 256)
    pfx = ((const float4*)(Wemb_dec + (size_t)start_tok_p[0] * HDIM))[tid];
  __syncthreads();

  uint rnd = 0;
  int gstep = 0;

  for (int t = 0; t < nsteps; ++t) {
    if (tid < 256) x4[tid] = pfx;
    __syncthreads();

    // ---- LSTM gates (weights in registers; half-wave reduce) ----
    {
      const float4* xf = (const float4*)&x4[0];
      float g = bsd;
#pragma unroll
      for (int c = 0; c < 8; ++c) {
        g += dot4(wid[c], xf[l32 + 32 * c]);
        g += dot4(whd[c], h4[l32 + 32 * c]);
      }
      g = wred32(g);
      float* gcur = gates + (gstep & 1) * 4096;
      if (l32 == 0) astf(&gcur[r_d], g);
    }
    gbar(arrive, done, ++rnd);  // (A)

    // issue leftover-row load EARLY: hides under gates read + activations
    uint4 qv;
    if (MODE == 2 && haveq) qv = qp[0];

    {
      const float* gcur = gates + (gstep & 1) * 4096;
      float h2acc = 0.f;
#pragma unroll
      for (int q = 0; q < 2; ++q) {
        int j = tid + q * NTHR_D;
        float ig = aldf(&gcur[j]),        fg = aldf(&gcur[j + 1024]);
        float gv = aldf(&gcur[j + 2048]), og = aldf(&gcur[j + 3072]);
        float ii = 1.f / (1.f + expf(-ig));
        float ff = 1.f / (1.f + expf(-fg));
        float gt = tanhf(gv);
        float oo = 1.f / (1.f + expf(-og));
        float cc = ff * c_l[j] + ii * gt;
        c_l[j] = cc;
        float hv = oo * tanhf(cc);
        h_s[j] = hv;
        hscan[((((j >> 2) ^ ((j >> 5) & 7)) << 2) | (j & 3))] = hv;
        h2acc += hv * hv;
      }
      float h2 = wred64(h2acc);
      if (lane == 0) red_n[wave] = h2;
    }
    ++gstep;
    __syncthreads();

    // ---- logit scan ----
    if (MODE >= 1) {
      const float4* hs4 = (const float4*)hscan;
      const int c0 = 4 * lane;
      float4 h0 = hs4[(c0 + 0) ^ (((c0 + 0) >> 3) & 7)];
      float4 h1 = hs4[(c0 + 1) ^ (((c0 + 1) >> 3) & 7)];
      float4 h2 = hs4[(c0 + 2) ^ (((c0 + 2) >> 3) & 7)];
      float4 h3 = hs4[(c0 + 3) ^ (((c0 + 3) >> 3) & 7)];
      if (MODE == 2) {
        // 4 LDS batches (rows 0..127)
#pragma unroll
        for (int k = 0; k < 4; ++k) {
          int jb = 4 * wave + 32 * k;
          const uint4* b0 = w8l + (jb << 6) + lane;
          uint4 u0 = b0[0], u1 = b0[64], u2 = b0[128], u3 = b0[192];
          float a0 = dot16_fp8(u0, h0, h1, h2, h3);
          float a1 = dot16_fp8(u1, h0, h1, h2, h3);
          float a2 = dot16_fp8(u2, h0, h1, h2, h3);
          float a3 = dot16_fp8(u3, h0, h1, h2, h3);
          a0 = wred64(a0); a1 = wred64(a1); a2 = wred64(a2); a3 = wred64(a3);
          if (lane == 0) {
            e_l[jb]     = a0 + bo_l[jb];
            e_l[jb + 1] = a1 + bo_l[jb + 1];
            e_l[jb + 2] = a2 + bo_l[jb + 2];
            e_l[jb + 3] = a3 + bo_l[jb + 3];
          }
        }
        // 2 global batches (rows 128..191, L2-resident)
#pragma unroll
        for (int k = 0; k < 2; ++k) {
          int jb = 128 + 4 * wave + 32 * k;
          const uint4* b0 = W8 + (((size_t)(start + jb)) << 6) + lane;
          uint4 u0 = b0[0], u1 = b0[64], u2 = b0[128], u3 = b0[192];
          float a0 = dot16_fp8(u0, h0, h1, h2, h3);
          float a1 = dot16_fp8(u1, h0, h1, h2, h3);
          float a2 = dot16_fp8(u2, h0, h1, h2, h3);
          float a3 = dot16_fp8(u3, h0, h1, h2, h3);
          a0 = wred64(a0); a1 = wred64(a1); a2 = wred64(a2); a3 = wred64(a3);
          if (lane == 0) {
            e_l[jb]     = a0 + bo_l[jb];
            e_l[jb + 1] = a1 + bo_l[jb + 1];
            e_l[jb + 2] = a2 + bo_l[jb + 2];
            e_l[jb + 3] = a3 + bo_l[jb + 3];
          }
        }
        // leftover rows 192..count-1, one row per wave (early-issued qv)
        if (haveq) {
          float a = dot16_fp8(qv, h0, h1, h2, h3);
          a = wred64(a);
          if (lane == 0) e_l[192 + wave] = a + bo_l[192 + wave];
        }
      } else {  // MODE 1: fp8 global stream
        for (int jb = wave * 4; jb < count; jb += NWAVE_D * 4) {
          int n_ = count - jb;
          const uint4* b0 = W8 + (((size_t)(start + jb)) << 6) + lane;
          uint4 u0 = b0[0];
          uint4 u1 = b0[n_ > 1 ? 64 : 0];
          uint4 u2 = b0[n_ > 2 ? 128 : 0];
          uint4 u3 = b0[n_ > 3 ? 192 : 0];
          float a0 = dot16_fp8(u0, h0, h1, h2, h3);
          float a1 = dot16_fp8(u1, h0, h1, h2, h3);
          float a2 = dot16_fp8(u2, h0, h1, h2, h3);
          float a3 = dot16_fp8(u3, h0, h1, h2, h3);
          a0 = wred64(a0); a1 = wred64(a1); a2 = wred64(a2); a3 = wred64(a3);
          if (lane == 0) {
            e_l[jb] = a0 + bo_l[jb];
            if (n_ > 1) e_l[jb + 1] = a1 + bo_l[jb + 1];
            if (n_ > 2) e_l[jb + 2] = a2 + bo_l[jb + 2];
            if (n_ > 3) e_l[jb + 3] = a3 + bo_l[jb + 3];
          }
        }
      }
    } else {  // MODE 0: fp32 global
      for (int jb = wave * 4; jb < count; jb += NWAVE_D * 4) {
        int n_ = count - jb;
        const float4* r0 = (const float4*)(W_out + (size_t)(start + jb) * HDIM);
        const float4* r1 = (const float4*)(W_out + (size_t)(start + jb + (n_ > 1 ? 1 : 0)) * HDIM);
        const float4* r2 = (const float4*)(W_out + (size_t)(start + jb + (n_ > 2 ? 2 : 0)) * HDIM);
        const float4* r3 = (const float4*)(W_out + (size_t)(start + jb + (n_ > 3 ? 3 : 0)) * HDIM);
        float a0 = 0.f, a1 = 0.f, a2 = 0.f, a3 = 0.f;
#pragma unroll
        for (int c = 0; c < 4; ++c) {
          float4 hh = h4[lane + 64 * c];
          a0 += dot4(r0[lane + 64 * c], hh);
          a1 += dot4(r1[lane + 64 * c], hh);
          a2 += dot4(r2[lane + 64 * c], hh);
          a3 += dot4(r3[lane + 64 * c], hh);
        }
        a0 = wred64(a0); a1 = wred64(a1); a2 = wred64(a2); a3 = wred64(a3);
        if (lane == 0) {
          e_l[jb] = a0 + bo_l[jb];
          if (n_ > 1) e_l[jb + 1] = a1 + bo_l[jb + 1];
          if (n_ > 2) e_l[jb + 2] = a2 + bo_l[jb + 2];
          if (n_ > 3) e_l[jb + 3] = a3 + bo_l[jb + 3];
        }
      }
    }
    __syncthreads();

    // ---- block-local max/argmax (np.argmax tie-break: lowest index) ----
    float m_soft; int i_soft;
    {
      float v = -INFINITY; int idx = 0x7fffffff;
      if (tid < count) { v = e_l[tid]; idx = start + tid; }
      wmax64(v, idx);
      if (lane == 0) { red_v[wave] = v; red_i[wave] = idx; }
    }
    __syncthreads();
    {
      float v = red_v[0]; int idx = red_i[0];
#pragma unroll
      for (int w = 1; w < NWAVE_D; ++w) {
        float v2 = red_v[w]; int i2 = red_i[w];
        if (v2 > v || (v2 == v && i2 < idx)) { v = v2; idx = i2; }
      }
      m_soft = v; i_soft = idx;
    }

    // ---- exp partial ----
    float pe = (tid < count) ? expf(e_l[tid] - m_soft) : 0.f;
    {
      float ls = wred64(pe);
      if (lane == 0) red_s[wave] = ls;
    }

    // ---- fp32 rescore of near-max candidates (argmax-exact) ----
    float m_arg = m_soft; int i_arg = i_soft;
    if (MODE >= 1) {
      float nrm2 = 0.f;
#pragma unroll
      for (int w = 0; w < NWAVE_D; ++w) nrm2 += red_n[w];
      float delta = 0.005f * sqrtf(nrm2) + 1e-6f;   // ~10 sigma of fp8 error
      float bv = -INFINITY; int bi = 0x7fffffff;
      for (int j = wave; j < count; j += NWAVE_D) {
        if (e_l[j] >= m_soft - delta) {
          const float4* w = (const float4*)(W_out + (size_t)(start + j) * HDIM);
          float a = 0.f;
#pragma unroll
          for (int c = 0; c < 4; ++c) a += dot4(w[lane + 64 * c], h4[lane + 64 * c]);
          a = wred64(a) + bo_l[j];
          if (a > bv) { bv = a; bi = start + j; }
        }
      }
      if (lane == 0) { red_v2[wave] = bv; red_i2[wave] = bi; }
    }
    __syncthreads();
    float lsum = 0.f;
#pragma unroll
    for (int w = 0; w < NWAVE_D; ++w) lsum += red_s[w];
    if (MODE >= 1) {
      float v = red_v2[0]; int idx = red_i2[0];
#pragma unroll
      for (int w = 1; w < NWAVE_D; ++w) {
        float v2 = red_v2[w]; int i2 = red_i2[w];
        if (v2 > v || (v2 == v && i2 < idx)) { v = v2; idx = i2; }
      }
      m_arg = v; i_arg = idx;
    }

    if (tid == 0) {
      astf(&psoft[blk], m_soft); astf(&pargv[blk], m_arg);
      asti(&pargi[blk], i_arg);  astf(&psum[blk], lsum);
    }

    // ---- barrier B with payload ----
    ++rnd;
    __syncthreads();
    int tokn; float lmax, Ssum;
    if (blk == 0) {
      if (tid >= 1 && tid < NBLK) {
        const uint* slot = arrive + tid * 32;
        while (ald(slot) < rnd) __builtin_amdgcn_s_sleep(1);
      }
      __syncthreads();
      float v = -INFINITY, m = -INFINITY, mysum = 0.f, myms = 0.f;
      int idx = 0x7fffffff;
      if (tid < NBLK) {
        v     = aldf(&pargv[tid]);
        idx   = aldi(&pargi[tid]);
        m     = aldf(&psoft[tid]);
        mysum = aldf(&psum[tid]);
        myms  = m;
      }
      wmax64(v, idx);
      float mm = wvmax64(m);
      if (lane == 0 && wave < 4) { red_v[wave] = v; red_i[wave] = idx; red_n[wave] = mm; }
      __syncthreads();
      {
        float vv = red_v[0]; int ii2 = red_i[0]; float mmax = red_n[0];
#pragma unroll
        for (int w = 1; w < 4; ++w) {
          float v2 = red_v[w]; int i2 = red_i[w];
          if (v2 > vv || (v2 == vv && i2 < ii2)) { vv = v2; ii2 = i2; }
          mmax = fmaxf(mmax, red_n[w]);
        }
        tokn = ii2; lmax = mmax;
      }
      {
        float s = (tid < NBLK) ? mysum * expf(myms - lmax) : 0.f;
        s = wred64(s);
        if (lane == 0 && wave < 4) red_s[wave] = s;
      }
      __syncthreads();
      Ssum = red_s[0] + red_s[1] + red_s[2] + red_s[3];
      if (tid < 32) {
        uint* dl = done + tid * 32;
        ast(dl + 1, (uint)tokn);
        ast(dl + 2, __float_as_uint(lmax));
        ast(dl + 3, __float_as_uint(Ssum));
        fence_vm();
        ast(dl, rnd);
      }
    } else {
      if (tid == 0) {
        fence_vm();
        ast(arrive + blk * 32, rnd);
        const uint* dl = done + (blk >> 3) * 32;
        while (ald(dl) < rnd) __builtin_amdgcn_s_sleep(1);
        sh_tok  = (int)ald(dl + 1);
        sh_lmax = __uint_as_float(ald(dl + 2));
        sh_S    = __uint_as_float(ald(dl + 3));
      }
      __syncthreads();
      tokn = sh_tok; lmax = sh_lmax; Ssum = sh_S;
    }

    if (tid < 256)
      pfx = ((const float4*)(Wemb_dec + (size_t)tokn * HDIM))[tid];

    float scale = expf(m_soft - lmax) / Ssum;
    if (tid < count)
      out[(size_t)nsteps + (size_t)t * VDIM + start + tid] = pe * scale;
    if (blk == 0 && tid == 0) out[t] = (float)tokn;
  }
}

extern "C" void kernel_launch(void* const* d_in, const int* in_sizes, int n_in,
                              void* d_out, int out_size, void* d_ws, size_t ws_size,
                              hipStream_t stream) {
  const int*   source      = (const int*)d_in[0];
  const int*   n_steps_p   = (const int*)d_in[1];
  const int*   start_tok_p = (const int*)d_in[2];
  const float* Wemb_enc    = (const float*)d_in[3];
  const float* W_ih_e      = (const float*)d_in[4];
  const float* W_hh_e      = (const float*)d_in[5];
  const float* b_ih_e      = (const float*)d_in[6];
  const float* b_hh_e      = (const float*)d_in[7];
  const float* Wemb_dec    = (const float*)d_in[8];
  const float* W_ih_d      = (const float*)d_in[9];
  const float* W_hh_d      = (const float*)d_in[10];
  const float* b_ih_d      = (const float*)d_in[11];
  const float* b_hh_d      = (const float*)d_in[12];
  const float* W_out       = (const float*)d_in[13];
  const float* b_out       = (const float*)d_in[14];
  float*       out         = (float*)d_out;
  int          S           = in_sizes[0];

  char* ws = (char*)d_ws;
  float* gates  = (float*)(ws + WS_GATES);
  float* psoft  = (float*)(ws + WS_PSOFT);
  float* pargv  = (float*)(ws + WS_PARGV);
  int*   pargi  = (int*)  (ws + WS_PARGI);
  float* psum   = (float*)(ws + WS_PSUM);
  uint*  arrE   = (uint*) (ws + WS_ARRE);
  uint*  donE   = (uint*) (ws + WS_DONE_E);
  uint*  arrD   = (uint*) (ws + WS_ARRD);
  uint*  donD   = (uint*) (ws + WS_DONE_D);
  float* hc     = (float*)(ws + WS_HC);
  uint4* W8     = (uint4*)(ws + WS_W8);

  bool use_q8 = ws_size >= (size_t)WS_W8 + W8_BYTES;

  hipMemsetAsync(ws + WS_ZOFF, 0, WS_ZLEN, stream);

  if (use_q8)
    conv8_kernel<<<2048, 256, 0, stream>>>(W_out, W8, VDIM * HDIM / 16);

  void* eargs[] = { &source, &S, &Wemb_enc, &W_ih_e, &W_hh_e, &b_ih_e, &b_hh_e,
                    &gates, &arrE, &donE, &hc };
  hipLaunchCooperativeKernel((void*)enc_kernel, dim3(NBLK), dim3(NTHR),
                             eargs, 0, stream);

  void* dargs[] = { &n_steps_p, &start_tok_p, &Wemb_dec, &W_ih_d, &W_hh_d,
                    &b_ih_d, &b_hh_d, &W_out, &b_out, &W8, &out, &gates,
                    &psoft, &pargv, &pargi, &psum, &arrD, &donD, &hc };

  bool launched = false;
  if (use_q8) {
    int dyn = LROWS * 1024;   // 131072 B dynamic
    (void)hipFuncSetAttribute((const void*)dec_kernel<2>,
                              hipFuncAttributeMaxDynamicSharedMemorySize, dyn);
    hipError_t err = hipLaunchCooperativeKernel((void*)dec_kernel<2>,
                                                dim3(NBLK), dim3(NTHR_D),
                                                dargs, dyn, stream);
    if (err == hipSuccess) launched = true;
    else (void)hipGetLastError();   // clear error state
    if (!launched) {
      err = hipLaunchCooperativeKernel((void*)dec_kernel<1>, dim3(NBLK),
                                       dim3(NTHR_D), dargs, 0, stream);
      if (err == hipSuccess) launched = true;
    }
  }
  if (!launched) {
    hipLaunchCooperativeKernel((void*)dec_kernel<0>, dim3(NBLK), dim3(NTHR_D),
                               dargs, 0, stream);
  }
}